// Round 2
// baseline (54.307 us; speedup 1.0000x reference)
//
#include <hip/hip_runtime.h>
#include <hip/hip_bf16.h>

// SASA-style local self-attention, fully fused. All I/O float32.
// B=4, C=64, H=W=96, g=8, og=ig=8, k=7, pad=3.
// One block = one (b, group) x one 16x16 spatial tile.
// Phase 1: per-group weights + relative-pos emb -> LDS.
// Phase 2: k,v for the 22x22 halo tile (grouped 1x1 conv) -> LDS (f32).
// Phase 3: one pixel/thread; loop over 8 output channels, 49-tap
//          softmax attention reading k/v from LDS, emb broadcast from LDS.

constexpr int Bc = 4, Cc = 64, Hc = 96, Wc = 96;
constexpr int G = 8, OG = 8, IG = 8, KK = 7, PAD = 3;
constexpr int TH = 16, TW = 16;
constexpr int SH = TH + KK - 1;   // 22 halo rows
constexpr int SWD = 22;           // halo cols (data)
constexpr int SW = 24;            // LDS row stride (floats) -> uniform 2-way bank alias (free)
constexpr int TILES_H = Hc / TH;  // 6
constexpr int TILES_W = Wc / TW;  // 6
constexpr int PLANE = Hc * Wc;    // 9216

__global__ __launch_bounds__(256)
void sasa_fused_kernel(const float* __restrict__ x,
                       const float* __restrict__ wq,
                       const float* __restrict__ wk,
                       const float* __restrict__ wv,
                       const float* __restrict__ h_emb,
                       const float* __restrict__ w_emb,
                       float* __restrict__ out)
{
    __shared__ float ks[OG][SH][SW];
    __shared__ float vs[OG][SH][SW];
    __shared__ float wqs[OG * IG];
    __shared__ float wks[OG * IG];
    __shared__ float wvs[OG * IG];
    __shared__ float embs[OG * KK * KK];

    const int tid = threadIdx.x;
    const int bid = blockIdx.x;
    const int tile = bid % (TILES_H * TILES_W);
    const int bg   = bid / (TILES_H * TILES_W);
    const int b  = bg >> 3;
    const int gi = bg & 7;
    const int th0 = (tile / TILES_W) * TH;
    const int tw0 = (tile % TILES_W) * TW;

    // ---- Phase 1: weights + emb to LDS ----
    if (tid < OG * IG) {
        wqs[tid] = wq[gi * OG * IG + tid];
        wks[tid] = wk[gi * OG * IG + tid];
        wvs[tid] = wv[gi * OG * IG + tid];
    }
    for (int e = tid; e < OG * KK * KK; e += 256) {
        int oc = e / (KK * KK);
        int p  = e % (KK * KK);
        int i = p / KK, j = p % KK;
        float ev = (oc < OG / 2)
            ? h_emb[(gi * (OG / 2) + oc) * KK + i]
            : w_emb[(gi * (OG / 2) + (oc - OG / 2)) * KK + j];
        embs[e] = ev;
    }
    __syncthreads();

    // ---- Phase 2: k,v over halo tile ----
    const float* xb = x + (size_t)(b * Cc + gi * IG) * PLANE;
    for (int e = tid; e < SH * SWD; e += 256) {
        int hy = e / SWD, hx = e % SWD;
        int gy = th0 + hy - PAD;
        int gx = tw0 + hx - PAD;
        bool valid = ((unsigned)gy < (unsigned)Hc) && ((unsigned)gx < (unsigned)Wc);
        float xv[IG];
        #pragma unroll
        for (int i = 0; i < IG; ++i)
            xv[i] = valid ? xb[i * PLANE + gy * Wc + gx] : 0.0f;
        #pragma unroll
        for (int oc = 0; oc < OG; ++oc) {
            float ka = 0.0f, va = 0.0f;
            #pragma unroll
            for (int i = 0; i < IG; ++i) {
                ka += xv[i] * wks[oc * IG + i];
                va += xv[i] * wvs[oc * IG + i];
            }
            ks[oc][hy][hx] = ka;
            vs[oc][hy][hx] = va;
        }
    }
    __syncthreads();

    // ---- Phase 3: attention, one pixel per thread, loop over oc ----
    const int ty = tid >> 4, tx = tid & 15;
    const int h = th0 + ty, w = tw0 + tx;

    float xc[IG];
    #pragma unroll
    for (int i = 0; i < IG; ++i)
        xc[i] = xb[i * PLANE + h * Wc + w];

    const size_t obase = ((size_t)(b * Cc + gi * OG) * Hc + h) * Wc + w;

    for (int oc = 0; oc < OG; ++oc) {
        float qv = 0.0f;
        #pragma unroll
        for (int i = 0; i < IG; ++i) qv += xc[i] * wqs[oc * IG + i];

        float l[KK * KK];
        float m = -1e30f;
        #pragma unroll
        for (int p = 0; p < KK * KK; ++p) {
            int i = p / KK, j = p % KK;
            float lv = qv * (ks[oc][ty + i][tx + j] + embs[oc * KK * KK + p]);
            l[p] = lv;
            m = fmaxf(m, lv);
        }
        float s = 0.0f, o = 0.0f;
        #pragma unroll
        for (int p = 0; p < KK * KK; ++p) {
            int i = p / KK, j = p % KK;
            float e = __expf(l[p] - m);
            s += e;
            o += e * vs[oc][ty + i][tx + j];
        }
        out[obase + (size_t)oc * PLANE] = o / s;
    }
}

extern "C" void kernel_launch(void* const* d_in, const int* in_sizes, int n_in,
                              void* d_out, int out_size, void* d_ws, size_t ws_size,
                              hipStream_t stream)
{
    const float* x     = (const float*)d_in[0];
    const float* wq    = (const float*)d_in[1];
    const float* wk    = (const float*)d_in[2];
    const float* wv    = (const float*)d_in[3];
    const float* h_emb = (const float*)d_in[4];
    const float* w_emb = (const float*)d_in[5];
    float* out = (float*)d_out;

    const int nblocks = Bc * G * TILES_H * TILES_W;  // 4*8*36 = 1152
    sasa_fused_kernel<<<nblocks, 256, 0, stream>>>(x, wq, wk, wv, h_emb, w_emb, out);
}

// Round 3
// 47.832 us; speedup vs baseline: 1.1354x; 1.1354x over previous
//
#include <hip/hip_runtime.h>

// SASA-style local self-attention, fully fused, f32 I/O.
// B=4, C=64, H=W=96, g=8, og=ig=8, k=7, pad=3.
// One block = (b, group, channel-half) x 16x16 tile; 4 output channels/block.
// half=0 -> channels 0..3 (h_emb, row-constant), half=1 -> 4..7 (w_emb, col-constant).
// Weights/emb read via block-uniform global loads (scalarized); only k,v staged in LDS.
// Softmax without max-subtraction (logits bounded << 88) -> single pass, no l[] array.

constexpr int Bc = 4, Cc = 64, Hc = 96, Wc = 96;
constexpr int G = 8, OG = 8, IG = 8, KK = 7, PAD = 3;
constexpr int TH = 16, TW = 16;
constexpr int SH = TH + KK - 1;   // 22 halo rows
constexpr int SWD = TW + KK - 1;  // 22 halo cols (data)
constexpr int SW = 24;            // LDS row stride -> uniform 2-way bank alias (free)
constexpr int TILES_H = Hc / TH, TILES_W = Wc / TW;   // 6 x 6
constexpr int TILES = TILES_H * TILES_W;              // 36
constexpr int PLANE = Hc * Wc;    // 9216
constexpr int OCB = 4;            // output channels per block

__global__ __launch_bounds__(256, 8)
void sasa_kernel(const float* __restrict__ x,
                 const float* __restrict__ wq,
                 const float* __restrict__ wk,
                 const float* __restrict__ wv,
                 const float* __restrict__ h_emb,
                 const float* __restrict__ w_emb,
                 float* __restrict__ out)
{
    __shared__ float ks[OCB][SH][SW];
    __shared__ float vs[OCB][SH][SW];

    const int tid  = threadIdx.x;
    const int bid  = blockIdx.x;
    const int tile = bid % TILES;
    const int rest = bid / TILES;
    const int half = rest & 1;
    const int bg   = rest >> 1;
    const int gi   = bg & 7;
    const int b    = bg >> 3;
    const int th0  = (tile / TILES_W) * TH;
    const int tw0  = (tile % TILES_W) * TW;

    const float* xb  = x  + (size_t)(b * Cc + gi * IG) * PLANE;
    const float* wkg = wk + gi * OG * IG + half * OCB * IG;   // [4][8], block-uniform
    const float* wvg = wv + gi * OG * IG + half * OCB * IG;
    const float* wqg = wq + gi * OG * IG + half * OCB * IG;

    // ---- Phase 1: k,v over halo tile (grouped 1x1 conv) -> LDS ----
    for (int e = tid; e < SH * SWD; e += 256) {
        const int hy = e / SWD, hx = e - (e / SWD) * SWD;
        const int gy = th0 + hy - PAD;
        const int gx = tw0 + hx - PAD;
        const bool valid = ((unsigned)gy < (unsigned)Hc) && ((unsigned)gx < (unsigned)Wc);
        float xv[IG];
        #pragma unroll
        for (int i = 0; i < IG; ++i)
            xv[i] = valid ? xb[i * PLANE + gy * Wc + gx] : 0.0f;
        #pragma unroll
        for (int oc = 0; oc < OCB; ++oc) {
            float ka = 0.0f, va = 0.0f;
            #pragma unroll
            for (int i = 0; i < IG; ++i) {
                ka = fmaf(xv[i], wkg[oc * IG + i], ka);
                va = fmaf(xv[i], wvg[oc * IG + i], va);
            }
            ks[oc][hy][hx] = ka;
            vs[oc][hy][hx] = va;
        }
    }
    __syncthreads();

    // ---- Phase 2: attention, one pixel per thread ----
    const int ty = tid >> 4, tx = tid & 15;
    const int h = th0 + ty, w = tw0 + tx;

    float xc[IG];
    #pragma unroll
    for (int i = 0; i < IG; ++i)
        xc[i] = xb[i * PLANE + h * Wc + w];

    const float* eb = (half ? w_emb : h_emb) + gi * (OG / 2) * KK;  // block-uniform
    float* ob = out + (size_t)(b * Cc + gi * OG + half * OCB) * PLANE + h * Wc + w;

    #pragma unroll 1
    for (int oc = 0; oc < OCB; ++oc) {
        float qv = 0.0f;
        #pragma unroll
        for (int i = 0; i < IG; ++i) qv = fmaf(xc[i], wqg[oc * IG + i], qv);

        float qe[KK];
        #pragma unroll
        for (int t = 0; t < KK; ++t) qe[t] = qv * eb[oc * KK + t];

        float s0 = 0.f, s1 = 0.f, o0 = 0.f, o1 = 0.f;
        if (half == 0) {
            // emb varies along patch ROW index i (constant across j)
            #pragma unroll
            for (int i = 0; i < KK; ++i) {
                const float qei = qe[i];
                #pragma unroll
                for (int j = 0; j < KK; ++j) {
                    float ev = __expf(fmaf(qv, ks[oc][ty + i][tx + j], qei));
                    if (i & 1) { s1 += ev; o1 = fmaf(ev, vs[oc][ty + i][tx + j], o1); }
                    else       { s0 += ev; o0 = fmaf(ev, vs[oc][ty + i][tx + j], o0); }
                }
            }
        } else {
            // emb varies along patch COL index j
            #pragma unroll
            for (int i = 0; i < KK; ++i) {
                #pragma unroll
                for (int j = 0; j < KK; ++j) {
                    float ev = __expf(fmaf(qv, ks[oc][ty + i][tx + j], qe[j]));
                    if (i & 1) { s1 += ev; o1 = fmaf(ev, vs[oc][ty + i][tx + j], o1); }
                    else       { s0 += ev; o0 = fmaf(ev, vs[oc][ty + i][tx + j], o0); }
                }
            }
        }
        ob[oc * PLANE] = (o0 + o1) / (s0 + s1);
    }
}

extern "C" void kernel_launch(void* const* d_in, const int* in_sizes, int n_in,
                              void* d_out, int out_size, void* d_ws, size_t ws_size,
                              hipStream_t stream)
{
    const float* x     = (const float*)d_in[0];
    const float* wq    = (const float*)d_in[1];
    const float* wk    = (const float*)d_in[2];
    const float* wv    = (const float*)d_in[3];
    const float* h_emb = (const float*)d_in[4];
    const float* w_emb = (const float*)d_in[5];
    float* out = (float*)d_out;

    const int nblocks = Bc * G * 2 * TILES;  // 4*8*2*36 = 2304
    sasa_kernel<<<nblocks, 256, 0, stream>>>(x, wq, wk, wv, h_emb, w_emb, out);
}

// Round 4
// 28.609 us; speedup vs baseline: 1.8982x; 1.6719x over previous
//
#include <hip/hip_runtime.h>

// SASA local self-attention, fully fused, f32 I/O.
// B=4, C=64, H=W=96, g=8, og=ig=8, k=7, pad=3.
// Block = (b, group, channel-half) x 32x16 tile; 4 output channels/block.
// 256 threads, each owns 2 vertically-adjacent pixels (rows share 7/8 halo rows).
// k,v interleaved as float2 in LDS -> ds_read_b64; each halo row-segment read
// once, used for both pixels. exp2-prescaled softmax (no max-subtraction;
// logits bounded << 127). XCD-aware block swizzle (1152 = 8*144, bijective).

constexpr int Bc = 4, Cc = 64, Hc = 96, Wc = 96;
constexpr int G = 8, OG = 8, IG = 8, KK = 7, PAD = 3;
constexpr int TH = 32, TW = 16;
constexpr int SH = TH + KK - 1;    // 38 halo rows
constexpr int SWD = TW + KK - 1;   // 22 halo cols (data)
constexpr int SW2 = 24;            // LDS row stride in float2
constexpr int TILES_H = Hc / TH, TILES_W = Wc / TW;  // 3 x 6
constexpr int TILES = TILES_H * TILES_W;             // 18
constexpr int PLANE = Hc * Wc;
constexpr int OCB = 4;
constexpr float LOG2E = 1.4426950408889634f;

// Full per-oc attention loop; HALFC must be a literal 0/1 so qe indexing is static.
#define OC_LOOP(HALFC)                                                            \
  _Pragma("unroll 1")                                                             \
  for (int oc = 0; oc < OCB; ++oc) {                                              \
    float qv0 = 0.f, qv1 = 0.f;                                                   \
    _Pragma("unroll")                                                             \
    for (int i2 = 0; i2 < IG; ++i2) {                                             \
      const float wqi = wqg[oc * IG + i2];                                        \
      qv0 = fmaf(xc0[i2], wqi, qv0);                                              \
      qv1 = fmaf(xc1[i2], wqi, qv1);                                              \
    }                                                                             \
    qv0 *= LOG2E; qv1 *= LOG2E;                                                   \
    float qe0[KK], qe1[KK];                                                       \
    _Pragma("unroll")                                                             \
    for (int t = 0; t < KK; ++t) {                                                \
      const float e = ebase[oc * KK + t];                                         \
      qe0[t] = qv0 * e; qe1[t] = qv1 * e;                                         \
    }                                                                             \
    float s0a = 0.f, s0b = 0.f, o0a = 0.f, o0b = 0.f;                             \
    float s1a = 0.f, s1b = 0.f, o1a = 0.f, o1b = 0.f;                             \
    const float2* rp = &kvs[oc][r0][tx];                                          \
    _Pragma("unroll")                                                             \
    for (int i = 0; i < 8; ++i) {                                                 \
      float2 row[KK];                                                             \
      _Pragma("unroll")                                                           \
      for (int j = 0; j < KK; ++j) row[j] = rp[i * SW2 + j];                      \
      if (i < 7) {                                                                \
        _Pragma("unroll")                                                         \
        for (int j = 0; j < KK; ++j) {                                            \
          const float ev = __builtin_amdgcn_exp2f(                                \
              fmaf(qv0, row[j].x, (HALFC) ? qe0[j] : qe0[i]));                    \
          if (j & 1) { s0b += ev; o0b = fmaf(ev, row[j].y, o0b); }                \
          else       { s0a += ev; o0a = fmaf(ev, row[j].y, o0a); }                \
        }                                                                         \
      }                                                                           \
      if (i >= 1) {                                                               \
        _Pragma("unroll")                                                         \
        for (int j = 0; j < KK; ++j) {                                            \
          const float ev = __builtin_amdgcn_exp2f(                                \
              fmaf(qv1, row[j].x, (HALFC) ? qe1[j] : qe1[i - 1]));                \
          if (j & 1) { s1b += ev; o1b = fmaf(ev, row[j].y, o1b); }                \
          else       { s1a += ev; o1a = fmaf(ev, row[j].y, o1a); }                \
        }                                                                         \
      }                                                                           \
    }                                                                             \
    ob[oc * PLANE]      = (o0a + o0b) * __builtin_amdgcn_rcpf(s0a + s0b);         \
    ob[oc * PLANE + Wc] = (o1a + o1b) * __builtin_amdgcn_rcpf(s1a + s1b);         \
  }

__global__ __launch_bounds__(256, 4)
void sasa_kernel(const float* __restrict__ x,
                 const float* __restrict__ wq,
                 const float* __restrict__ wk,
                 const float* __restrict__ wv,
                 const float* __restrict__ h_emb,
                 const float* __restrict__ w_emb,
                 float* __restrict__ out)
{
    __shared__ float2 kvs[OCB][SH][SW2];   // 29184 B

    const int tid = threadIdx.x;
    // XCD-aware swizzle: give each XCD 144 consecutive logical blocks (= 4 full
    // (b,g) x-panels) so halo re-reads hit the same XCD's L2.
    const int L = (blockIdx.x & 7) * (Bc * G * 2 * TILES / 8) + (blockIdx.x >> 3);
    const int tile = L % TILES;
    const int rest = L / TILES;
    const int half = rest & 1;
    const int gi   = (rest >> 1) & 7;
    const int b    = rest >> 4;
    const int th0  = (tile / TILES_W) * TH;
    const int tw0  = (tile % TILES_W) * TW;

    const float* xb  = x  + (size_t)(b * Cc + gi * IG) * PLANE;
    const float* wqg = wq + gi * OG * IG + half * OCB * IG;  // block-uniform
    const float* wkg = wk + gi * OG * IG + half * OCB * IG;
    const float* wvg = wv + gi * OG * IG + half * OCB * IG;
    const float* ebase = (half ? w_emb : h_emb) + gi * (OG / 2) * KK;

    // ---- Phase 1: k,v (grouped 1x1 conv) over 38x22 halo -> LDS float2 ----
    for (int e = tid; e < SH * SWD; e += 256) {
        const int hy = e / SWD, hx = e - hy * SWD;
        const int gy = th0 + hy - PAD;
        const int gx = tw0 + hx - PAD;
        const bool valid = ((unsigned)gy < (unsigned)Hc) && ((unsigned)gx < (unsigned)Wc);
        float xv[IG];
        #pragma unroll
        for (int i = 0; i < IG; ++i)
            xv[i] = valid ? xb[i * PLANE + gy * Wc + gx] : 0.0f;
        #pragma unroll
        for (int oc = 0; oc < OCB; ++oc) {
            float ka = 0.f, va = 0.f;
            #pragma unroll
            for (int i = 0; i < IG; ++i) {
                ka = fmaf(xv[i], wkg[oc * IG + i], ka);
                va = fmaf(xv[i], wvg[oc * IG + i], va);
            }
            kvs[oc][hy][hx] = make_float2(ka, va);
        }
    }
    __syncthreads();

    // ---- Phase 2: attention; thread owns pixels (r0, tx) and (r0+1, tx) ----
    const int tx  = tid & 15;
    const int ty2 = tid >> 4;
    const int r0  = 2 * ty2;            // local rows r0, r0+1
    const int h0  = th0 + r0;
    const int wg  = tw0 + tx;

    float xc0[IG], xc1[IG];
    {
        const float* xp = xb + (size_t)h0 * Wc + wg;
        #pragma unroll
        for (int i = 0; i < IG; ++i) {
            xc0[i] = xp[i * PLANE];
            xc1[i] = xp[i * PLANE + Wc];
        }
    }

    float* ob = out + (size_t)(b * Cc + gi * OG + half * OCB) * PLANE
                    + (size_t)h0 * Wc + wg;

    if (half == 0) { OC_LOOP(0) } else { OC_LOOP(1) }
}

extern "C" void kernel_launch(void* const* d_in, const int* in_sizes, int n_in,
                              void* d_out, int out_size, void* d_ws, size_t ws_size,
                              hipStream_t stream)
{
    const float* x     = (const float*)d_in[0];
    const float* wq    = (const float*)d_in[1];
    const float* wk    = (const float*)d_in[2];
    const float* wv    = (const float*)d_in[3];
    const float* h_emb = (const float*)d_in[4];
    const float* w_emb = (const float*)d_in[5];
    float* out = (float*)d_out;

    const int nblocks = Bc * G * 2 * TILES;  // 1152 (divisible by 8)
    sasa_kernel<<<nblocks, 256, 0, stream>>>(x, wq, wk, wv, h_emb, w_emb, out);
}

// Round 5
// 28.567 us; speedup vs baseline: 1.9010x; 1.0015x over previous
//
#include <hip/hip_runtime.h>

// SASA local self-attention, fully fused, f32 I/O.
// B=4, C=64, H=W=96, g=8, og=ig=8, k=7, pad=3.
// Block = (b, group, channel-QUARTER) x 32x16 tile; 2 output channels/block.
// 256 threads, each owns 2 vertically-adjacent pixels (rows share 7/8 halo rows).
// k,v interleaved as float2 in LDS (row stride 25 -> uniform 2-way bank alias, free).
// exp2-prescaled softmax, no max-subtraction (logits bounded << 127).
// XCD-aware bijective block swizzle (2304 % 8 == 0).
// LDS 15.2 KB + launch_bounds(256,8) -> 8 blocks/CU = 32 waves/CU.

constexpr int Bc = 4, Cc = 64, Hc = 96, Wc = 96;
constexpr int G = 8, OG = 8, IG = 8, KK = 7, PAD = 3;
constexpr int TH = 32, TW = 16;
constexpr int SH = TH + KK - 1;    // 38 halo rows
constexpr int SWD = TW + KK - 1;   // 22 halo cols (data)
constexpr int SW2 = 25;            // LDS row stride in float2 units
constexpr int TILES_H = Hc / TH, TILES_W = Wc / TW;  // 3 x 6
constexpr int TILES = TILES_H * TILES_W;             // 18
constexpr int PLANE = Hc * Wc;
constexpr int OCB = 2;             // output channels per block (4 quarters)
constexpr int NB = Bc * G * 4 * TILES;               // 2304
constexpr float LOG2E = 1.4426950408889634f;

// Attention tap loops. HALFC literal 0 (emb varies with row i) / 1 (with col j).
#define OC_LOOP(HALFC)                                                            \
  _Pragma("unroll 1")                                                             \
  for (int oc = 0; oc < OCB; ++oc) {                                              \
    const float qv0 = qvs[oc][0], qv1 = qvs[oc][1];                               \
    float qe0[KK], qe1[KK];                                                       \
    _Pragma("unroll")                                                             \
    for (int t = 0; t < KK; ++t) {                                                \
      const float e = eb[oc * KK + t];                                            \
      qe0[t] = qv0 * e; qe1[t] = qv1 * e;                                         \
    }                                                                             \
    float s0a = 0.f, s0b = 0.f, o0a = 0.f, o0b = 0.f;                             \
    float s1a = 0.f, s1b = 0.f, o1a = 0.f, o1b = 0.f;                             \
    const float2* rp = &kvs[oc][r0][tx];                                          \
    _Pragma("unroll")                                                             \
    for (int i = 0; i < 8; ++i) {                                                 \
      float2 row[KK];                                                             \
      _Pragma("unroll")                                                           \
      for (int j = 0; j < KK; ++j) row[j] = rp[i * SW2 + j];                      \
      if (i < 7) {                                                                \
        _Pragma("unroll")                                                         \
        for (int j = 0; j < KK; ++j) {                                            \
          const float ev = __builtin_amdgcn_exp2f(                                \
              fmaf(qv0, row[j].x, (HALFC) ? qe0[j] : qe0[i]));                    \
          if (j & 1) { s0b += ev; o0b = fmaf(ev, row[j].y, o0b); }                \
          else       { s0a += ev; o0a = fmaf(ev, row[j].y, o0a); }                \
        }                                                                         \
      }                                                                           \
      if (i >= 1) {                                                               \
        _Pragma("unroll")                                                         \
        for (int j = 0; j < KK; ++j) {                                            \
          const float ev = __builtin_amdgcn_exp2f(                                \
              fmaf(qv1, row[j].x, (HALFC) ? qe1[j] : qe1[i - 1]));                \
          if (j & 1) { s1b += ev; o1b = fmaf(ev, row[j].y, o1b); }                \
          else       { s1a += ev; o1a = fmaf(ev, row[j].y, o1a); }                \
        }                                                                         \
      }                                                                           \
    }                                                                             \
    ob[oc * PLANE]      = (o0a + o0b) * __builtin_amdgcn_rcpf(s0a + s0b);         \
    ob[oc * PLANE + Wc] = (o1a + o1b) * __builtin_amdgcn_rcpf(s1a + s1b);         \
  }

__global__ __launch_bounds__(256, 8)
void sasa_kernel(const float* __restrict__ x,
                 const float* __restrict__ wq,
                 const float* __restrict__ wk,
                 const float* __restrict__ wv,
                 const float* __restrict__ h_emb,
                 const float* __restrict__ w_emb,
                 float* __restrict__ out)
{
    __shared__ float2 kvs[OCB][SH][SW2];   // 15200 B

    const int tid = threadIdx.x;
    // XCD-aware bijective swizzle: each XCD owns 288 consecutive logical blocks.
    const int L = (blockIdx.x & 7) * (NB / 8) + (blockIdx.x >> 3);
    const int tile    = L % TILES;
    const int rest    = L / TILES;
    const int quarter = rest & 3;          // channel pair: oc_global = quarter*2 + {0,1}
    const int gi      = (rest >> 2) & 7;
    const int b       = rest >> 5;
    const int half    = quarter >> 1;      // 0 -> h_emb, 1 -> w_emb
    const int th0     = (tile / TILES_W) * TH;
    const int tw0     = (tile % TILES_W) * TW;

    const float* xb  = x  + (size_t)(b * Cc + gi * IG) * PLANE;
    const float* wqg = wq + gi * OG * IG + quarter * OCB * IG;  // block-uniform
    const float* wkg = wk + gi * OG * IG + quarter * OCB * IG;
    const float* wvg = wv + gi * OG * IG + quarter * OCB * IG;
    const float* eb  = (half ? w_emb : h_emb) + gi * (OG / 2) * KK
                                              + (quarter & 1) * OCB * KK;

    // ---- q-pixel loads issued first so latency hides under phase 1 ----
    const int tx  = tid & 15;
    const int r0  = 2 * (tid >> 4);
    const int h0  = th0 + r0;
    const int wg  = tw0 + tx;
    float xc0[IG], xc1[IG];
    {
        const float* xp = xb + (size_t)h0 * Wc + wg;
        #pragma unroll
        for (int i = 0; i < IG; ++i) {
            xc0[i] = xp[i * PLANE];
            xc1[i] = xp[i * PLANE + Wc];
        }
    }

    // ---- Phase 1: k,v (grouped 1x1 conv) over 38x22 halo -> LDS float2 ----
    for (int e = tid; e < SH * SWD; e += 256) {
        const int hy = e / SWD, hx = e - hy * SWD;
        const int gy = th0 + hy - PAD;
        const int gx = tw0 + hx - PAD;
        const bool valid = ((unsigned)gy < (unsigned)Hc) && ((unsigned)gx < (unsigned)Wc);
        float xv[IG];
        #pragma unroll
        for (int i = 0; i < IG; ++i)
            xv[i] = valid ? xb[i * PLANE + gy * Wc + gx] : 0.0f;
        #pragma unroll
        for (int oc = 0; oc < OCB; ++oc) {
            float ka = 0.f, va = 0.f;
            #pragma unroll
            for (int i = 0; i < IG; ++i) {
                ka = fmaf(xv[i], wkg[oc * IG + i], ka);
                va = fmaf(xv[i], wvg[oc * IG + i], va);
            }
            kvs[oc][hy][hx] = make_float2(ka, va);
        }
    }

    // q projections before the barrier; xc registers retire here.
    float qvs[OCB][2];
    #pragma unroll
    for (int oc = 0; oc < OCB; ++oc) {
        float q0 = 0.f, q1 = 0.f;
        #pragma unroll
        for (int i = 0; i < IG; ++i) {
            const float wqi = wqg[oc * IG + i];
            q0 = fmaf(xc0[i], wqi, q0);
            q1 = fmaf(xc1[i], wqi, q1);
        }
        qvs[oc][0] = q0 * LOG2E;
        qvs[oc][1] = q1 * LOG2E;
    }
    __syncthreads();

    // ---- Phase 2: attention; thread owns pixels (r0, tx) and (r0+1, tx) ----
    float* ob = out + (size_t)(b * Cc + gi * OG + quarter * OCB) * PLANE
                    + (size_t)h0 * Wc + wg;

    if (half == 0) { OC_LOOP(0) } else { OC_LOOP(1) }
}

extern "C" void kernel_launch(void* const* d_in, const int* in_sizes, int n_in,
                              void* d_out, int out_size, void* d_ws, size_t ws_size,
                              hipStream_t stream)
{
    const float* x     = (const float*)d_in[0];
    const float* wq    = (const float*)d_in[1];
    const float* wk    = (const float*)d_in[2];
    const float* wv    = (const float*)d_in[3];
    const float* h_emb = (const float*)d_in[4];
    const float* w_emb = (const float*)d_in[5];
    float* out = (float*)d_out;

    sasa_kernel<<<NB, 256, 0, stream>>>(x, wq, wk, wv, h_emb, w_emb, out);
}